// Round 1
// baseline (252.464 us; speedup 1.0000x reference)
//
#include <hip/hip_runtime.h>

#define DEVINL __device__ __forceinline__

DEVINL float fmax4(float4 v) { return fmaxf(fmaxf(v.x, v.y), fmaxf(v.z, v.w)); }

// Fused: maxpool(t1,k=2)+tile2  + maxpool(t2,k=4)+tile4 + maxpool(t3,k=8)+tile8
//        + maxpool(t4,k=16)+tile16 + ff, then ReLU.  All fp32, NCHW.
// Shapes: t1 (8,128,56,56)  t2 (8,64,112,112)  t3 (8,32,224,224)
//         t4 (8,16,448,448) ff/out (8,256,28,28)
// Block = (pw-quarter, ph, b): pools 7 output columns for ALL channels into
// LDS (inputs read exactly once), then fuses 256ch x 7pw outputs from LDS.
__global__ __launch_bounds__(256) void fused_pool_relu(
    const float* __restrict__ t1, const float* __restrict__ t2,
    const float* __restrict__ t3, const float* __restrict__ t4,
    const float* __restrict__ ff, float* __restrict__ out)
{
    const int pwq = blockIdx.x;      // 0..3  (7 pooled cols each)
    const int ph  = blockIdx.y;      // 0..27
    const int b   = blockIdx.z;      // 0..7
    const int tid = threadIdx.x;     // 0..255
    const int pw0 = pwq * 7;

    __shared__ float p1[128 * 7];
    __shared__ float p2[64 * 7];
    __shared__ float p3[32 * 7];
    __shared__ float p4[16 * 7];

    // ---- t4: (8,16,448,448), k=16; 16 ch x 16 rows = 256 threads ----
    {
        const int c = tid >> 4, r = tid & 15;
        const float* row = t4 + ((b * 16 + c) * 448 + (ph * 16 + r)) * 448;
        #pragma unroll
        for (int pwl = 0; pwl < 7; ++pwl) {
            const float4* p = (const float4*)(row + (pw0 + pwl) * 16);
            float m = fmaxf(fmaxf(fmax4(p[0]), fmax4(p[1])),
                            fmaxf(fmax4(p[2]), fmax4(p[3])));
            m = fmaxf(m, __shfl_xor(m, 1));
            m = fmaxf(m, __shfl_xor(m, 2));
            m = fmaxf(m, __shfl_xor(m, 4));
            m = fmaxf(m, __shfl_xor(m, 8));
            if (r == 0) p4[c * 7 + pwl] = m;
        }
    }

    // ---- t3: (8,32,224,224), k=8; 32 ch x 8 rows ----
    {
        const int c = tid >> 3, r = tid & 7;
        const float* row = t3 + ((b * 32 + c) * 224 + (ph * 8 + r)) * 224;
        #pragma unroll
        for (int pwl = 0; pwl < 7; ++pwl) {
            const float4* p = (const float4*)(row + (pw0 + pwl) * 8);
            float m = fmaxf(fmax4(p[0]), fmax4(p[1]));
            m = fmaxf(m, __shfl_xor(m, 1));
            m = fmaxf(m, __shfl_xor(m, 2));
            m = fmaxf(m, __shfl_xor(m, 4));
            if (r == 0) p3[c * 7 + pwl] = m;
        }
    }

    // ---- t2: (8,64,112,112), k=4; 64 ch x 4 rows ----
    {
        const int c = tid >> 2, r = tid & 3;
        const float* row = t2 + ((b * 64 + c) * 112 + (ph * 4 + r)) * 112;
        #pragma unroll
        for (int pwl = 0; pwl < 7; ++pwl) {
            float4 v = *(const float4*)(row + (pw0 + pwl) * 4);
            float m = fmax4(v);
            m = fmaxf(m, __shfl_xor(m, 1));
            m = fmaxf(m, __shfl_xor(m, 2));
            if (r == 0) p2[c * 7 + pwl] = m;
        }
    }

    // ---- t1: (8,128,56,56), k=2; 128 ch x 2 rows ----
    {
        const int c = tid >> 1, r = tid & 1;
        const float* row = t1 + ((b * 128 + c) * 56 + (ph * 2 + r)) * 56;
        #pragma unroll
        for (int pwl = 0; pwl < 7; ++pwl) {
            float2 v = *(const float2*)(row + (pw0 + pwl) * 2);
            float m = fmaxf(v.x, v.y);
            m = fmaxf(m, __shfl_xor(m, 1));
            if (r == 0) p1[c * 7 + pwl] = m;
        }
    }

    __syncthreads();

    // ---- fusion epilogue: 256 ch x 7 pw outputs ----
    // out flat index (b,c,ph,pw) = b*200704 + c*784 + ph*28 + pw
    const int obase = b * 200704 + ph * 28 + pw0;
    #pragma unroll
    for (int it = 0; it < 7; ++it) {
        const int idx = it * 256 + tid;      // 0..1791
        const int c = idx / 7, pwl = idx % 7;
        const int o = obase + c * 784 + pwl;
        float v = p1[(c & 127) * 7 + pwl] + p2[(c & 63) * 7 + pwl]
                + p3[(c & 31) * 7 + pwl] + p4[(c & 15) * 7 + pwl] + ff[o];
        out[o] = fmaxf(v, 0.0f);
    }
}

extern "C" void kernel_launch(void* const* d_in, const int* in_sizes, int n_in,
                              void* d_out, int out_size, void* d_ws, size_t ws_size,
                              hipStream_t stream) {
    const float* t1 = (const float*)d_in[0];
    const float* t2 = (const float*)d_in[1];
    const float* t3 = (const float*)d_in[2];
    const float* t4 = (const float*)d_in[3];
    const float* ff = (const float*)d_in[4];
    float* out = (float*)d_out;

    dim3 grid(4, 28, 8);   // (pw-quarter, ph, b) = 896 blocks
    fused_pool_relu<<<grid, 256, 0, stream>>>(t1, t2, t3, t4, ff, out);
}

// Round 2
// 234.722 us; speedup vs baseline: 1.0756x; 1.0756x over previous
//
#include <hip/hip_runtime.h>

#define DEVINL __device__ __forceinline__

DEVINL float fmax4(float4 v) { return fmaxf(fmaxf(v.x, v.y), fmaxf(v.z, v.w)); }

// Fused: maxpool(t1,k=2)+tile2 + maxpool(t2,k=4)+tile4 + maxpool(t3,k=8)+tile8
//        + maxpool(t4,k=16)+tile16 + ff, then ReLU.  All fp32, NCHW.
// Shapes: t1 (8,128,56,56)  t2 (8,64,112,112)  t3 (8,32,224,224)
//         t4 (8,16,448,448) ff/out (8,256,28,28)
//
// R2: latency-bound fix. Each section loads ALL its window data into an
// explicit float4 register array first (t4: 16 float4 = 256 B/lane in
// flight), then reduces. 4 pooled cols per block -> grid 7x28x8 = 1568
// blocks (~6 blocks/CU). Epilogue is pow2: one float4 ff/out per thread.
__global__ __launch_bounds__(256) void fused_pool_relu(
    const float* __restrict__ t1, const float* __restrict__ t2,
    const float* __restrict__ t3, const float* __restrict__ t4,
    const float* __restrict__ ff, float* __restrict__ out)
{
    const int pwq = blockIdx.x;      // 0..6  (4 pooled cols each)
    const int ph  = blockIdx.y;      // 0..27
    const int b   = blockIdx.z;      // 0..7
    const int tid = threadIdx.x;     // 0..255
    const int pw0 = pwq * 4;

    __shared__ __align__(16) float p1[128 * 4];
    __shared__ __align__(16) float p2[64 * 4];
    __shared__ __align__(16) float p3[32 * 4];
    __shared__ __align__(16) float p4[16 * 4];

    // ---- t4: (8,16,448,448), k=16; 16 ch x 16 rows = 256 threads ----
    // lane reads 4 windows x 64 B = 256 B contiguous (16 float4 in flight)
    {
        const int c = tid >> 4, r = tid & 15;
        const float4* row =
            (const float4*)(t4 + ((b * 16 + c) * 448 + (ph * 16 + r)) * 448 + pw0 * 16);
        float4 v[16];
        #pragma unroll
        for (int i = 0; i < 16; ++i) v[i] = row[i];
        #pragma unroll
        for (int pwl = 0; pwl < 4; ++pwl) {
            float m = fmaxf(fmaxf(fmax4(v[pwl * 4 + 0]), fmax4(v[pwl * 4 + 1])),
                            fmaxf(fmax4(v[pwl * 4 + 2]), fmax4(v[pwl * 4 + 3])));
            m = fmaxf(m, __shfl_xor(m, 1));
            m = fmaxf(m, __shfl_xor(m, 2));
            m = fmaxf(m, __shfl_xor(m, 4));
            m = fmaxf(m, __shfl_xor(m, 8));
            if (r == 0) p4[c * 4 + pwl] = m;
        }
    }

    // ---- t3: (8,32,224,224), k=8; 32 ch x 8 rows ----
    {
        const int c = tid >> 3, r = tid & 7;
        const float4* row =
            (const float4*)(t3 + ((b * 32 + c) * 224 + (ph * 8 + r)) * 224 + pw0 * 8);
        float4 v[8];
        #pragma unroll
        for (int i = 0; i < 8; ++i) v[i] = row[i];
        #pragma unroll
        for (int pwl = 0; pwl < 4; ++pwl) {
            float m = fmaxf(fmax4(v[pwl * 2 + 0]), fmax4(v[pwl * 2 + 1]));
            m = fmaxf(m, __shfl_xor(m, 1));
            m = fmaxf(m, __shfl_xor(m, 2));
            m = fmaxf(m, __shfl_xor(m, 4));
            if (r == 0) p3[c * 4 + pwl] = m;
        }
    }

    // ---- t2: (8,64,112,112), k=4; 64 ch x 4 rows ----
    {
        const int c = tid >> 2, r = tid & 3;
        const float4* row =
            (const float4*)(t2 + ((b * 64 + c) * 112 + (ph * 4 + r)) * 112 + pw0 * 4);
        float4 v[4];
        #pragma unroll
        for (int i = 0; i < 4; ++i) v[i] = row[i];
        #pragma unroll
        for (int pwl = 0; pwl < 4; ++pwl) {
            float m = fmax4(v[pwl]);
            m = fmaxf(m, __shfl_xor(m, 1));
            m = fmaxf(m, __shfl_xor(m, 2));
            if (r == 0) p2[c * 4 + pwl] = m;
        }
    }

    // ---- t1: (8,128,56,56), k=2; 128 ch x 2 rows ----
    // one float4 covers two k=2 windows
    {
        const int c = tid >> 1, r = tid & 1;
        const float4* row =
            (const float4*)(t1 + ((b * 128 + c) * 56 + (ph * 2 + r)) * 56 + pw0 * 2);
        float4 v0 = row[0], v1 = row[1];
        float m0 = fmaxf(v0.x, v0.y), m1 = fmaxf(v0.z, v0.w);
        float m2 = fmaxf(v1.x, v1.y), m3 = fmaxf(v1.z, v1.w);
        m0 = fmaxf(m0, __shfl_xor(m0, 1));
        m1 = fmaxf(m1, __shfl_xor(m1, 1));
        m2 = fmaxf(m2, __shfl_xor(m2, 1));
        m3 = fmaxf(m3, __shfl_xor(m3, 1));
        if (r == 0) {
            p1[c * 4 + 0] = m0; p1[c * 4 + 1] = m1;
            p1[c * 4 + 2] = m2; p1[c * 4 + 3] = m3;
        }
    }

    __syncthreads();

    // ---- fusion epilogue: thread = channel, 4 pw as one float4 ----
    // out flat (b,c,ph,pw) = b*200704 + c*784 + ph*28 + pw; all /4 exact
    const int c = tid;
    const int o4 = (b * 200704 + c * 784 + ph * 28 + pw0) >> 2;
    const float4 f  = ((const float4*)ff)[o4];
    const float4 a1 = *(const float4*)&p1[(c & 127) * 4];
    const float4 a2 = *(const float4*)&p2[(c & 63) * 4];
    const float4 a3 = *(const float4*)&p3[(c & 31) * 4];
    const float4 a4 = *(const float4*)&p4[(c & 15) * 4];
    float4 o;
    o.x = fmaxf(a1.x + a2.x + a3.x + a4.x + f.x, 0.0f);
    o.y = fmaxf(a1.y + a2.y + a3.y + a4.y + f.y, 0.0f);
    o.z = fmaxf(a1.z + a2.z + a3.z + a4.z + f.z, 0.0f);
    o.w = fmaxf(a1.w + a2.w + a3.w + a4.w + f.w, 0.0f);
    ((float4*)out)[o4] = o;
}

extern "C" void kernel_launch(void* const* d_in, const int* in_sizes, int n_in,
                              void* d_out, int out_size, void* d_ws, size_t ws_size,
                              hipStream_t stream) {
    const float* t1 = (const float*)d_in[0];
    const float* t2 = (const float*)d_in[1];
    const float* t3 = (const float*)d_in[2];
    const float* t4 = (const float*)d_in[3];
    const float* ff = (const float*)d_in[4];
    float* out = (float*)d_out;

    dim3 grid(7, 28, 8);   // (pw-quarter, ph, b) = 1568 blocks
    fused_pool_relu<<<grid, 256, 0, stream>>>(t1, t2, t3, t4, ff, out);
}

// Round 3
// 229.570 us; speedup vs baseline: 1.0997x; 1.0224x over previous
//
#include <hip/hip_runtime.h>

#define DEVINL __device__ __forceinline__

DEVINL float fmax4(float4 v) { return fmaxf(fmaxf(v.x, v.y), fmaxf(v.z, v.w)); }
DEVINL float4 max44(float4 a, float4 b) {
    float4 r; r.x = fmaxf(a.x, b.x); r.y = fmaxf(a.y, b.y);
    r.z = fmaxf(a.z, b.z); r.w = fmaxf(a.w, b.w); return r;
}

// Fused: maxpool(t1,k=2)+tile2 + maxpool(t2,k=4)+tile4 + maxpool(t3,k=8)+tile8
//        + maxpool(t4,k=16)+tile16 + ff, then ReLU.  All fp32, NCHW.
// Shapes: t1 (8,128,56,56)  t2 (8,64,112,112)  t3 (8,32,224,224)
//         t4 (8,16,448,448) ff/out (8,256,28,28)
//
// R3: lane-CONSECUTIVE coalescing. A lane-group owns one (channel,row)
// segment of 4 pooled windows (t4: 16 lanes x float4 = 64 contiguous
// floats). Row-direction max = register accumulation over the row loop;
// window finish = <=2 shfl_xor steps. Each vmem instruction now touches
// ~10 cache lines instead of ~64 (R2's lane-per-row layout).
__global__ __launch_bounds__(256) void fused_pool_relu(
    const float* __restrict__ t1, const float* __restrict__ t2,
    const float* __restrict__ t3, const float* __restrict__ t4,
    const float* __restrict__ ff, float* __restrict__ out)
{
    const int pwq = blockIdx.x;      // 0..6  (4 pooled cols each)
    const int ph  = blockIdx.y;      // 0..27
    const int b   = blockIdx.z;      // 0..7
    const int tid = threadIdx.x;     // 0..255
    const int pw0 = pwq * 4;

    __shared__ __align__(16) float p1[128 * 4];
    __shared__ __align__(16) float p2[64 * 4];
    __shared__ __align__(16) float p3[32 * 4];
    __shared__ __align__(16) float p4[16 * 4];

    // ---- t4: (8,16,448,448), k=16. group=channel (16 lanes), 16 rows ----
    // lane l covers float4 #l of the 64-float segment (4 windows).
    {
        const int g = tid >> 4, l = tid & 15;
        const float* base = t4 + ((size_t)(b * 16 + g) * 448 + ph * 16) * 448
                          + pw0 * 16 + l * 4;
        // two half-batches of 8 in-flight loads each (keeps VGPR <= ~64)
        float4 v[8];
        #pragma unroll
        for (int r = 0; r < 8; ++r) v[r] = *(const float4*)(base + r * 448);
        float4 acc = v[0];
        #pragma unroll
        for (int r = 1; r < 8; ++r) acc = max44(acc, v[r]);
        #pragma unroll
        for (int r = 8; r < 16; ++r) v[r - 8] = *(const float4*)(base + r * 448);
        #pragma unroll
        for (int r = 0; r < 8; ++r) acc = max44(acc, v[r]);
        float m = fmax4(acc);                 // max of this lane's 4 floats
        m = fmaxf(m, __shfl_xor(m, 1));       // window = 4 consecutive lanes
        m = fmaxf(m, __shfl_xor(m, 2));
        if ((l & 3) == 0) p4[g * 4 + (l >> 2)] = m;
    }

    // ---- t3: (8,32,224,224), k=8. group=channel (8 lanes), 8 rows ----
    {
        const int g = tid >> 3, l = tid & 7;
        const float* base = t3 + ((size_t)(b * 32 + g) * 224 + ph * 8) * 224
                          + pw0 * 8 + l * 4;
        float4 v[8];
        #pragma unroll
        for (int r = 0; r < 8; ++r) v[r] = *(const float4*)(base + r * 224);
        float4 acc = v[0];
        #pragma unroll
        for (int r = 1; r < 8; ++r) acc = max44(acc, v[r]);
        float m = fmax4(acc);
        m = fmaxf(m, __shfl_xor(m, 1));       // window = 2 consecutive lanes
        if ((l & 1) == 0) p3[g * 4 + (l >> 1)] = m;
    }

    // ---- t2: (8,64,112,112), k=4. group=channel (4 lanes), 4 rows ----
    // one float4 IS one window: no shuffle needed.
    {
        const int g = tid >> 2, l = tid & 3;
        const float* base = t2 + ((size_t)(b * 64 + g) * 112 + ph * 4) * 112
                          + pw0 * 4 + l * 4;
        float4 v[4];
        #pragma unroll
        for (int r = 0; r < 4; ++r) v[r] = *(const float4*)(base + r * 112);
        float4 acc = max44(max44(v[0], v[1]), max44(v[2], v[3]));
        p2[g * 4 + l] = fmax4(acc);
    }

    // ---- t1: (8,128,56,56), k=2. group=channel (2 lanes), 2 rows ----
    // one float4 covers two k=2 windows.
    {
        const int g = tid >> 1, l = tid & 1;
        const float* base = t1 + ((size_t)(b * 128 + g) * 56 + ph * 2) * 56
                          + pw0 * 2 + l * 4;
        float4 v0 = *(const float4*)(base);
        float4 v1 = *(const float4*)(base + 56);
        float4 a = max44(v0, v1);
        p1[g * 4 + l * 2 + 0] = fmaxf(a.x, a.y);
        p1[g * 4 + l * 2 + 1] = fmaxf(a.z, a.w);
    }

    __syncthreads();

    // ---- fusion epilogue: thread = channel, 4 pw as one float4 ----
    // out flat (b,c,ph,pw) = b*200704 + c*784 + ph*28 + pw; /4 exact
    const int c = tid;
    const int o4 = (b * 200704 + c * 784 + ph * 28 + pw0) >> 2;
    const float4 f  = ((const float4*)ff)[o4];
    const float4 a1 = *(const float4*)&p1[(c & 127) * 4];
    const float4 a2 = *(const float4*)&p2[(c & 63) * 4];
    const float4 a3 = *(const float4*)&p3[(c & 31) * 4];
    const float4 a4 = *(const float4*)&p4[(c & 15) * 4];
    float4 o;
    o.x = fmaxf(a1.x + a2.x + a3.x + a4.x + f.x, 0.0f);
    o.y = fmaxf(a1.y + a2.y + a3.y + a4.y + f.y, 0.0f);
    o.z = fmaxf(a1.z + a2.z + a3.z + a4.z + f.z, 0.0f);
    o.w = fmaxf(a1.w + a2.w + a3.w + a4.w + f.w, 0.0f);
    ((float4*)out)[o4] = o;
}

extern "C" void kernel_launch(void* const* d_in, const int* in_sizes, int n_in,
                              void* d_out, int out_size, void* d_ws, size_t ws_size,
                              hipStream_t stream) {
    const float* t1 = (const float*)d_in[0];
    const float* t2 = (const float*)d_in[1];
    const float* t3 = (const float*)d_in[2];
    const float* t4 = (const float*)d_in[3];
    const float* ff = (const float*)d_in[4];
    float* out = (float*)d_out;

    dim3 grid(7, 28, 8);   // (pw-quarter, ph, b) = 1568 blocks
    fused_pool_relu<<<grid, 256, 0, stream>>>(t1, t2, t3, t4, ff, out);
}

// Round 4
// 226.866 us; speedup vs baseline: 1.1128x; 1.0119x over previous
//
#include <hip/hip_runtime.h>

#define DEVINL __device__ __forceinline__

DEVINL float fmax4(float4 v) { return fmaxf(fmaxf(v.x, v.y), fmaxf(v.z, v.w)); }
DEVINL float4 max44(float4 a, float4 b) {
    float4 r; r.x = fmaxf(a.x, b.x); r.y = fmaxf(a.y, b.y);
    r.z = fmaxf(a.z, b.z); r.w = fmaxf(a.w, b.w); return r;
}

// ---------------- two-phase design (R4) ----------------
// Phase 1: each WAVE independently pools one contiguous band of one input
// into ws. No inter-wave deps; 21504 waves (84/CU). Streams are contiguous
// (copy-like). Wave-private LDS (448 floats) does the row/col transpose.
// Phase 2: elementwise combine: out = relu(p1[c%128]+p2[c%64]+p3[c%32]
//          +p4[c%16]+ff), fully coalesced.
//
// ws float offsets: p1[8][128][28][28] @0, p2[8][64][28][28] @802816,
//                   p3[8][32][28][28] @1204224, p4[8][16][28][28] @1404928
#define O1 0
#define O2 802816
#define O3 1204224
#define O4 1404928
#define WS_FLOATS 1505280

// wave-task ranges
#define W_T4 3584            // (b*16+c)=128 x ph=28         band 16x448
#define W_T3 10752           // + 7168: (b*32+c)=256 x 28    band 8x224
#define W_T2 14336           // + 3584: (b*64+c)=512 x phq=7 band 16x112
#define W_T1 21504           // + 7168: (b*128+c)=1024 x 7   band 8x56

__global__ __launch_bounds__(256, 4) void pool_all(
    const float* __restrict__ t1, const float* __restrict__ t2,
    const float* __restrict__ t3, const float* __restrict__ t4,
    float* __restrict__ ws)
{
    __shared__ __align__(16) float scratch[4 * 448];
    const int tid  = threadIdx.x;
    const int lane = tid & 63;
    const int w    = blockIdx.x * 4 + (tid >> 6);
    float* sm = &scratch[(tid >> 6) * 448];

    // ---------------- stage A: load + reduce + LDS write ----------------
    if (w < W_T4) {
        // t4 (8,16,448,448) k=16: band (cb,ph) = 16 rows x 448 = 7168 floats
        const int ph = w % 28, cb = w / 28;
        const float* base = t4 + (size_t)cb * 200704 + ph * 7168;
        float4 acc[7];
        #pragma unroll
        for (int k = 0; k < 7; ++k)
            acc[k] = *(const float4*)(base + (k * 64 + lane) * 4);
        #pragma unroll
        for (int g = 1; g < 4; ++g) {
            float4 v[7];
            #pragma unroll
            for (int k = 0; k < 7; ++k)
                v[k] = *(const float4*)(base + g * 1792 + (k * 64 + lane) * 4);
            #pragma unroll
            for (int k = 0; k < 7; ++k) acc[k] = max44(acc[k], v[k]);
        }
        // p = k*64+lane: rowres = p/112 (rows {r,r+4,r+8,r+12}), col4 = p%112
        #pragma unroll
        for (int k = 0; k < 7; ++k) {
            const int p = k * 64 + lane;
            sm[(p / 112) * 112 + (p % 112)] = fmax4(acc[k]);
        }
    } else if (w < W_T3) {
        // t3 (8,32,224,224) k=8: band = 8 rows x 224 = 1792 floats
        const int t = w - W_T4;
        const int ph = t % 28, cb = t / 28;
        const float* base = t3 + (size_t)cb * 50176 + ph * 1792;
        #pragma unroll
        for (int k = 0; k < 7; ++k) {
            float4 v = *(const float4*)(base + (k * 64 + lane) * 4);
            const int p = k * 64 + lane;     // row = p/56, col4 = p%56
            sm[(p % 56) * 8 + (p / 56)] = fmax4(v);
        }
    } else if (w < W_T2) {
        // t2 (8,64,112,112) k=4: band (cb,phq) = 16 rows x 112 = 1792 floats
        const int t = w - W_T3;
        const int phq = t % 7, cb = t / 7;
        const float* base = t2 + (size_t)cb * 12544 + phq * 1792;
        #pragma unroll
        for (int k = 0; k < 7; ++k) {
            float4 v = *(const float4*)(base + (k * 64 + lane) * 4);
            const int p = k * 64 + lane;     // row = p/28 (0..15), col4 = p%28
            sm[(p % 28) * 16 + (p / 28)] = fmax4(v);   // one k=4 window/row
        }
    } else {
        // t1 (8,128,56,56) k=2: band (cb,phq) = 8 rows x 56 = 448 floats
        const int t = w - W_T2;
        const int phq = t % 7, cb = t / 7;
        const float* base = t1 + (size_t)cb * 3136 + phq * 448;
        #pragma unroll
        for (int k = 0; k < 7; ++k) {
            const float v = base[k * 64 + lane];
            const int p = k * 64 + lane;     // row = p/56 (0..7), col = p%56
            sm[(p % 56) * 8 + (p / 56)] = v;
        }
    }

    __syncthreads();   // one barrier; all waves of the block hit exactly one

    // ---------------- stage B: LDS gather + store ----------------
    if (w < W_T4) {
        const int ph = w % 28, cb = w / 28;
        if (lane < 28) {
            float4 a = *(const float4*)&sm[0 * 112 + 4 * lane];
            float4 b = *(const float4*)&sm[1 * 112 + 4 * lane];
            float4 c = *(const float4*)&sm[2 * 112 + 4 * lane];
            float4 d = *(const float4*)&sm[3 * 112 + 4 * lane];
            ws[O4 + cb * 784 + ph * 28 + lane] =
                fmax4(max44(max44(a, b), max44(c, d)));
        }
    } else if (w < W_T3) {
        const int t = w - W_T4;
        const int ph = t % 28, cb = t / 28;
        if (lane < 28) {
            float4 a = *(const float4*)&sm[16 * lane + 0];
            float4 b = *(const float4*)&sm[16 * lane + 4];
            float4 c = *(const float4*)&sm[16 * lane + 8];
            float4 d = *(const float4*)&sm[16 * lane + 12];
            ws[O3 + cb * 784 + ph * 28 + lane] =
                fmax4(max44(max44(a, b), max44(c, d)));
        }
    } else if (w < W_T2) {
        const int t = w - W_T3;
        const int phq = t % 7, cb = t / 7;
        if (lane < 56) {
            #pragma unroll
            for (int h = 0; h < 2; ++h) {
                const int o = lane + h * 56;          // 0..111 = pr*28+j
                const int pr = o / 28, j = o % 28;
                float4 v = *(const float4*)&sm[j * 16 + pr * 4];
                ws[O2 + cb * 784 + phq * 112 + o] = fmax4(v);
            }
        }
    } else {
        const int t = w - W_T2;
        const int phq = t % 7, cb = t / 7;
        if (lane < 56) {
            #pragma unroll
            for (int h = 0; h < 2; ++h) {
                const int o = lane + h * 56;          // 0..111 = pr*28+j
                const int pr = o / 28, j = o % 28;
                float2 a = *(const float2*)&sm[16 * j + 2 * pr];
                float2 b = *(const float2*)&sm[16 * j + 8 + 2 * pr];
                ws[O1 + cb * 784 + phq * 112 + o] =
                    fmaxf(fmaxf(a.x, a.y), fmaxf(b.x, b.y));
            }
        }
    }
}

__global__ __launch_bounds__(256) void combine(
    const float* __restrict__ ws, const float* __restrict__ ff,
    float* __restrict__ out)
{
    const int i4 = blockIdx.x * 256 + threadIdx.x;   // out float4 index
    const int pw4 = i4 % 7;
    const int ph  = (i4 / 7) % 28;
    const int c   = (i4 / 196) % 256;
    const int b   = i4 / 50176;
    const int ppw = ph * 7 + pw4;
    const float4* W = (const float4*)ws;
    float4 a1 = W[O1 / 4 + (b * 128 + (c & 127)) * 196 + ppw];
    float4 a2 = W[O2 / 4 + (b * 64  + (c & 63))  * 196 + ppw];
    float4 a3 = W[O3 / 4 + (b * 32  + (c & 31))  * 196 + ppw];
    float4 a4 = W[O4 / 4 + (b * 16  + (c & 15))  * 196 + ppw];
    float4 f  = ((const float4*)ff)[i4];
    float4 o;
    o.x = fmaxf(a1.x + a2.x + a3.x + a4.x + f.x, 0.0f);
    o.y = fmaxf(a1.y + a2.y + a3.y + a4.y + f.y, 0.0f);
    o.z = fmaxf(a1.z + a2.z + a3.z + a4.z + f.z, 0.0f);
    o.w = fmaxf(a1.w + a2.w + a3.w + a4.w + f.w, 0.0f);
    ((float4*)out)[i4] = o;
}

// ---------------- fallback (R3 single-kernel) if ws too small ----------------
__global__ __launch_bounds__(256) void fused_pool_relu(
    const float* __restrict__ t1, const float* __restrict__ t2,
    const float* __restrict__ t3, const float* __restrict__ t4,
    const float* __restrict__ ff, float* __restrict__ out)
{
    const int pwq = blockIdx.x, ph = blockIdx.y, b = blockIdx.z;
    const int tid = threadIdx.x;
    const int pw0 = pwq * 4;
    __shared__ __align__(16) float p1[128 * 4];
    __shared__ __align__(16) float p2[64 * 4];
    __shared__ __align__(16) float p3[32 * 4];
    __shared__ __align__(16) float p4[16 * 4];
    {
        const int g = tid >> 4, l = tid & 15;
        const float* base = t4 + ((size_t)(b * 16 + g) * 448 + ph * 16) * 448
                          + pw0 * 16 + l * 4;
        float4 v[8];
        #pragma unroll
        for (int r = 0; r < 8; ++r) v[r] = *(const float4*)(base + r * 448);
        float4 acc = v[0];
        #pragma unroll
        for (int r = 1; r < 8; ++r) acc = max44(acc, v[r]);
        #pragma unroll
        for (int r = 8; r < 16; ++r) v[r - 8] = *(const float4*)(base + r * 448);
        #pragma unroll
        for (int r = 0; r < 8; ++r) acc = max44(acc, v[r]);
        float m = fmax4(acc);
        m = fmaxf(m, __shfl_xor(m, 1));
        m = fmaxf(m, __shfl_xor(m, 2));
        if ((l & 3) == 0) p4[g * 4 + (l >> 2)] = m;
    }
    {
        const int g = tid >> 3, l = tid & 7;
        const float* base = t3 + ((size_t)(b * 32 + g) * 224 + ph * 8) * 224
                          + pw0 * 8 + l * 4;
        float4 v[8];
        #pragma unroll
        for (int r = 0; r < 8; ++r) v[r] = *(const float4*)(base + r * 224);
        float4 acc = v[0];
        #pragma unroll
        for (int r = 1; r < 8; ++r) acc = max44(acc, v[r]);
        float m = fmax4(acc);
        m = fmaxf(m, __shfl_xor(m, 1));
        if ((l & 1) == 0) p3[g * 4 + (l >> 1)] = m;
    }
    {
        const int g = tid >> 2, l = tid & 3;
        const float* base = t2 + ((size_t)(b * 64 + g) * 112 + ph * 4) * 112
                          + pw0 * 4 + l * 4;
        float4 v[4];
        #pragma unroll
        for (int r = 0; r < 4; ++r) v[r] = *(const float4*)(base + r * 112);
        p2[g * 4 + l] = fmax4(max44(max44(v[0], v[1]), max44(v[2], v[3])));
    }
    {
        const int g = tid >> 1, l = tid & 1;
        const float* base = t1 + ((size_t)(b * 128 + g) * 56 + ph * 2) * 56
                          + pw0 * 2 + l * 4;
        float4 a = max44(*(const float4*)(base), *(const float4*)(base + 56));
        p1[g * 4 + l * 2 + 0] = fmaxf(a.x, a.y);
        p1[g * 4 + l * 2 + 1] = fmaxf(a.z, a.w);
    }
    __syncthreads();
    const int c = tid;
    const int o4 = (b * 200704 + c * 784 + ph * 28 + pw0) >> 2;
    const float4 f  = ((const float4*)ff)[o4];
    const float4 a1 = *(const float4*)&p1[(c & 127) * 4];
    const float4 a2 = *(const float4*)&p2[(c & 63) * 4];
    const float4 a3 = *(const float4*)&p3[(c & 31) * 4];
    const float4 a4 = *(const float4*)&p4[(c & 15) * 4];
    float4 o;
    o.x = fmaxf(a1.x + a2.x + a3.x + a4.x + f.x, 0.0f);
    o.y = fmaxf(a1.y + a2.y + a3.y + a4.y + f.y, 0.0f);
    o.z = fmaxf(a1.z + a2.z + a3.z + a4.z + f.z, 0.0f);
    o.w = fmaxf(a1.w + a2.w + a3.w + a4.w + f.w, 0.0f);
    ((float4*)out)[o4] = o;
}

extern "C" void kernel_launch(void* const* d_in, const int* in_sizes, int n_in,
                              void* d_out, int out_size, void* d_ws, size_t ws_size,
                              hipStream_t stream) {
    const float* t1 = (const float*)d_in[0];
    const float* t2 = (const float*)d_in[1];
    const float* t3 = (const float*)d_in[2];
    const float* t4 = (const float*)d_in[3];
    const float* ff = (const float*)d_in[4];
    float* out = (float*)d_out;

    if (ws_size >= (size_t)WS_FLOATS * sizeof(float)) {
        float* ws = (float*)d_ws;
        pool_all<<<W_T1 / 4, 256, 0, stream>>>(t1, t2, t3, t4, ws);
        combine<<<1568, 256, 0, stream>>>(ws, ff, out);
    } else {
        dim3 grid(7, 28, 8);
        fused_pool_relu<<<grid, 256, 0, stream>>>(t1, t2, t3, t4, ff, out);
    }
}

// Round 5
// 224.716 us; speedup vs baseline: 1.1235x; 1.0096x over previous
//
#include <hip/hip_runtime.h>

#define DEVINL __device__ __forceinline__

DEVINL float fmax4(float4 v) { return fmaxf(fmaxf(v.x, v.y), fmaxf(v.z, v.w)); }
DEVINL float4 max44(float4 a, float4 b) {
    float4 r; r.x = fmaxf(a.x, b.x); r.y = fmaxf(a.y, b.y);
    r.z = fmaxf(a.z, b.z); r.w = fmaxf(a.w, b.w); return r;
}

// Compile-time memory barrier: loads above cannot sink below it, so all
// batched loads are issued back-to-back and stay in flight together.
#define MEMBAR() asm volatile("" ::: "memory")

// ---------------- two-phase design (R5) ----------------
// Phase 1: one wave = one contiguous input band -> pooled row(s) in ws.
//   - forced MLP: load batches pinned by MEMBAR (14 float4 in flight for t4)
//   - LDS layouts are identity / stride-2 => conflict-free (m136: 2-way free)
//   - no __syncthreads: LDS slices are wave-private
// Phase 2: elementwise combine (coalesced).
//
// ws float offsets: p1[8][128][28][28] @0, p2[8][64][28][28] @802816,
//                   p3[8][32][28][28] @1204224, p4[8][16][28][28] @1404928
#define O1 0
#define O2 802816
#define O3 1204224
#define O4 1404928
#define WS_FLOATS 1505280

// wave-task ranges
#define W_T4 3584            // (b*16+c)=128 x ph=28          band 16x448
#define W_T3 10752           // +7168: (b*32+c)=256 x ph=28   band 8x224
#define W_T2 14336           // +3584: (b*64+c)=512 x phq=7   band 16x112
#define W_T1 21504           // +7168: (b*128+c)=1024 x phq=7 band 8x56

__global__ __launch_bounds__(256, 4) void pool_all(
    const float* __restrict__ t1, const float* __restrict__ t2,
    const float* __restrict__ t3, const float* __restrict__ t4,
    float* __restrict__ ws)
{
    __shared__ __align__(16) float scratch[4 * 448];
    const int tid  = threadIdx.x;
    const int lane = tid & 63;
    const int w    = blockIdx.x * 4 + (tid >> 6);
    float* sm = &scratch[(tid >> 6) * 448];

    if (w < W_T4) {
        // t4 (8,16,448,448) k=16: band (cb,ph) = 16 rows x 448 = 7168 floats.
        // Chunk g = rows 4g..4g+3 (1792 floats). Position p=k*64+lane:
        // r = p/112 (row class), col4 = p%112 (4 cols). acc = max over g.
        const int ph = w % 28, cb = w / 28;
        const float* base = t4 + (size_t)cb * 200704 + ph * 7168 + 4 * lane;
        float4 v[14], acc[7];
        // batch A: chunks g=0,1 -- 14 loads pinned in flight
        #pragma unroll
        for (int k = 0; k < 7; ++k) v[k]     = *(const float4*)(base + k * 256);
        #pragma unroll
        for (int k = 0; k < 7; ++k) v[7 + k] = *(const float4*)(base + 1792 + k * 256);
        MEMBAR();
        #pragma unroll
        for (int k = 0; k < 7; ++k) acc[k] = max44(v[k], v[7 + k]);
        // batch B: chunks g=2,3
        #pragma unroll
        for (int k = 0; k < 7; ++k) v[k]     = *(const float4*)(base + 3584 + k * 256);
        #pragma unroll
        for (int k = 0; k < 7; ++k) v[7 + k] = *(const float4*)(base + 5376 + k * 256);
        MEMBAR();
        #pragma unroll
        for (int k = 0; k < 7; ++k) acc[k] = max44(acc[k], max44(v[k], v[7 + k]));
        // identity LDS write (coalesced, conflict-free): sm[p] = col-max
        #pragma unroll
        for (int k = 0; k < 7; ++k) sm[k * 64 + lane] = fmax4(acc[k]);
        MEMBAR();
        // gather: out col j <- col4 4j..4j+3, row classes 0..3 (4-way, 4 insts)
        if (lane < 28) {
            float4 a = *(const float4*)&sm[0 * 112 + 4 * lane];
            float4 b = *(const float4*)&sm[1 * 112 + 4 * lane];
            float4 c = *(const float4*)&sm[2 * 112 + 4 * lane];
            float4 d = *(const float4*)&sm[3 * 112 + 4 * lane];
            ws[O4 + cb * 784 + ph * 28 + lane] =
                fmax4(max44(max44(a, b), max44(c, d)));
        }
    } else if (w < W_T3) {
        // t3 (8,32,224,224) k=8: band = 8 rows x 224 = 1792 floats.
        // p=k*64+lane: row = p/56 (0..7), col4 = p%56. Identity LDS layout.
        const int t = w - W_T4;
        const int ph = t % 28, cb = t / 28;
        const float* base = t3 + (size_t)cb * 50176 + ph * 1792 + 4 * lane;
        float4 v[7];
        #pragma unroll
        for (int k = 0; k < 7; ++k) v[k] = *(const float4*)(base + k * 256);
        MEMBAR();
        #pragma unroll
        for (int k = 0; k < 7; ++k) sm[k * 64 + lane] = fmax4(v[k]);
        MEMBAR();
        // out col j <- col4 {2j,2j+1}, rows 0..7 (lane stride 2 => 2-way free)
        if (lane < 28) {
            float m = fmaxf(sm[2 * lane], sm[2 * lane + 1]);
            #pragma unroll
            for (int r = 1; r < 8; ++r)
                m = fmaxf(m, fmaxf(sm[r * 56 + 2 * lane], sm[r * 56 + 2 * lane + 1]));
            ws[O3 + cb * 784 + ph * 28 + lane] = m;
        }
    } else if (w < W_T2) {
        // t2 (8,64,112,112) k=4: band (cb,phq) = 16 rows x 112 = 1792 floats.
        // p=k*64+lane: row = p/28 (0..15), pc = p%28. One float4 = one row's
        // 4-col window slice; identity LDS layout row*28+pc.
        const int t = w - W_T3;
        const int phq = t % 7, cb = t / 7;
        const float* base = t2 + (size_t)cb * 12544 + phq * 1792 + 4 * lane;
        float4 v[7];
        #pragma unroll
        for (int k = 0; k < 7; ++k) v[k] = *(const float4*)(base + k * 256);
        MEMBAR();
        #pragma unroll
        for (int k = 0; k < 7; ++k) sm[k * 64 + lane] = fmax4(v[k]);
        MEMBAR();
        // out (pr,pc): max rows 4pr..4pr+3 (lane stride 1 => conflict-free)
        if (lane < 56) {
            const int pr0 = lane / 28, pc = lane % 28;
            #pragma unroll
            for (int h = 0; h < 2; ++h) {
                const int pr = pr0 + 2 * h;
                float m = fmaxf(fmaxf(sm[(4 * pr + 0) * 28 + pc],
                                      sm[(4 * pr + 1) * 28 + pc]),
                                fmaxf(sm[(4 * pr + 2) * 28 + pc],
                                      sm[(4 * pr + 3) * 28 + pc]));
                ws[O2 + cb * 784 + phq * 112 + pr * 28 + pc] = m;
            }
        }
    } else {
        // t1 (8,128,56,56) k=2: band (cb,phq) = 8 rows x 56 = 448 floats.
        // float4 at lane<56: row = lane/14, c2 = lane%14 (rows 0..3); +224
        // gives rows 4..7. Half-max pairs stored as float2 (conflict-free).
        const int t = w - W_T2;
        const int phq = t % 7, cb = t / 7;
        const float* base = t1 + (size_t)cb * 3136 + phq * 448;
        if (lane < 56) {
            float4 a = *(const float4*)(base + 4 * lane);
            float4 b = *(const float4*)(base + 224 + 4 * lane);
            MEMBAR();
            float2 ha; ha.x = fmaxf(a.x, a.y); ha.y = fmaxf(a.z, a.w);
            float2 hb; hb.x = fmaxf(b.x, b.y); hb.y = fmaxf(b.z, b.w);
            const int ra = lane / 14, c2 = lane % 14;
            *(float2*)&sm[ra * 28 + 2 * c2]       = ha;   // rows 0..3
            *(float2*)&sm[(ra + 4) * 28 + 2 * c2] = hb;   // rows 4..7
        }
        MEMBAR();
        // out (pr,j): max rows 2pr,2pr+1 (lane stride 1 => conflict-free)
        if (lane < 56) {
            const int pr0 = lane / 28, j = lane % 28;
            #pragma unroll
            for (int h = 0; h < 2; ++h) {
                const int pr = pr0 + 2 * h;
                float m = fmaxf(sm[(2 * pr) * 28 + j], sm[(2 * pr + 1) * 28 + j]);
                ws[O1 + cb * 784 + phq * 112 + pr * 28 + j] = m;
            }
        }
    }
}

__global__ __launch_bounds__(256) void combine(
    const float* __restrict__ ws, const float* __restrict__ ff,
    float* __restrict__ out)
{
    const int i4 = blockIdx.x * 256 + threadIdx.x;   // out float4 index
    const int pw4 = i4 % 7;
    const int ph  = (i4 / 7) % 28;
    const int c   = (i4 / 196) % 256;
    const int b   = i4 / 50176;
    const int ppw = ph * 7 + pw4;
    const float4* W = (const float4*)ws;
    float4 a1 = W[O1 / 4 + (b * 128 + (c & 127)) * 196 + ppw];
    float4 a2 = W[O2 / 4 + (b * 64  + (c & 63))  * 196 + ppw];
    float4 a3 = W[O3 / 4 + (b * 32  + (c & 31))  * 196 + ppw];
    float4 a4 = W[O4 / 4 + (b * 16  + (c & 15))  * 196 + ppw];
    float4 f  = ((const float4*)ff)[i4];
    float4 o;
    o.x = fmaxf(a1.x + a2.x + a3.x + a4.x + f.x, 0.0f);
    o.y = fmaxf(a1.y + a2.y + a3.y + a4.y + f.y, 0.0f);
    o.z = fmaxf(a1.z + a2.z + a3.z + a4.z + f.z, 0.0f);
    o.w = fmaxf(a1.w + a2.w + a3.w + a4.w + f.w, 0.0f);
    ((float4*)out)[i4] = o;
}

// ---------------- fallback (R3 single-kernel) if ws too small ----------------
__global__ __launch_bounds__(256) void fused_pool_relu(
    const float* __restrict__ t1, const float* __restrict__ t2,
    const float* __restrict__ t3, const float* __restrict__ t4,
    const float* __restrict__ ff, float* __restrict__ out)
{
    const int pwq = blockIdx.x, ph = blockIdx.y, b = blockIdx.z;
    const int tid = threadIdx.x;
    const int pw0 = pwq * 4;
    __shared__ __align__(16) float p1[128 * 4];
    __shared__ __align__(16) float p2[64 * 4];
    __shared__ __align__(16) float p3[32 * 4];
    __shared__ __align__(16) float p4[16 * 4];
    {
        const int g = tid >> 4, l = tid & 15;
        const float* base = t4 + ((size_t)(b * 16 + g) * 448 + ph * 16) * 448
                          + pw0 * 16 + l * 4;
        float4 v[8];
        #pragma unroll
        for (int r = 0; r < 8; ++r) v[r] = *(const float4*)(base + r * 448);
        float4 acc = v[0];
        #pragma unroll
        for (int r = 1; r < 8; ++r) acc = max44(acc, v[r]);
        #pragma unroll
        for (int r = 8; r < 16; ++r) v[r - 8] = *(const float4*)(base + r * 448);
        #pragma unroll
        for (int r = 0; r < 8; ++r) acc = max44(acc, v[r]);
        float m = fmax4(acc);
        m = fmaxf(m, __shfl_xor(m, 1));
        m = fmaxf(m, __shfl_xor(m, 2));
        if ((l & 3) == 0) p4[g * 4 + (l >> 2)] = m;
    }
    {
        const int g = tid >> 3, l = tid & 7;
        const float* base = t3 + ((size_t)(b * 32 + g) * 224 + ph * 8) * 224
                          + pw0 * 8 + l * 4;
        float4 v[8];
        #pragma unroll
        for (int r = 0; r < 8; ++r) v[r] = *(const float4*)(base + r * 224);
        float4 acc = v[0];
        #pragma unroll
        for (int r = 1; r < 8; ++r) acc = max44(acc, v[r]);
        float m = fmax4(acc);
        m = fmaxf(m, __shfl_xor(m, 1));
        if ((l & 1) == 0) p3[g * 4 + (l >> 1)] = m;
    }
    {
        const int g = tid >> 2, l = tid & 3;
        const float* base = t2 + ((size_t)(b * 64 + g) * 112 + ph * 4) * 112
                          + pw0 * 4 + l * 4;
        float4 v[4];
        #pragma unroll
        for (int r = 0; r < 4; ++r) v[r] = *(const float4*)(base + r * 112);
        p2[g * 4 + l] = fmax4(max44(max44(v[0], v[1]), max44(v[2], v[3])));
    }
    {
        const int g = tid >> 1, l = tid & 1;
        const float* base = t1 + ((size_t)(b * 128 + g) * 56 + ph * 2) * 56
                          + pw0 * 2 + l * 4;
        float4 a = max44(*(const float4*)(base), *(const float4*)(base + 56));
        p1[g * 4 + l * 2 + 0] = fmaxf(a.x, a.y);
        p1[g * 4 + l * 2 + 1] = fmaxf(a.z, a.w);
    }
    __syncthreads();
    const int c = tid;
    const int o4 = (b * 200704 + c * 784 + ph * 28 + pw0) >> 2;
    const float4 f  = ((const float4*)ff)[o4];
    const float4 a1 = *(const float4*)&p1[(c & 127) * 4];
    const float4 a2 = *(const float4*)&p2[(c & 63) * 4];
    const float4 a3 = *(const float4*)&p3[(c & 31) * 4];
    const float4 a4 = *(const float4*)&p4[(c & 15) * 4];
    float4 o;
    o.x = fmaxf(a1.x + a2.x + a3.x + a4.x + f.x, 0.0f);
    o.y = fmaxf(a1.y + a2.y + a3.y + a4.y + f.y, 0.0f);
    o.z = fmaxf(a1.z + a2.z + a3.z + a4.z + f.z, 0.0f);
    o.w = fmaxf(a1.w + a2.w + a3.w + a4.w + f.w, 0.0f);
    ((float4*)out)[o4] = o;
}

extern "C" void kernel_launch(void* const* d_in, const int* in_sizes, int n_in,
                              void* d_out, int out_size, void* d_ws, size_t ws_size,
                              hipStream_t stream) {
    const float* t1 = (const float*)d_in[0];
    const float* t2 = (const float*)d_in[1];
    const float* t3 = (const float*)d_in[2];
    const float* t4 = (const float*)d_in[3];
    const float* ff = (const float*)d_in[4];
    float* out = (float*)d_out;

    if (ws_size >= (size_t)WS_FLOATS * sizeof(float)) {
        float* ws = (float*)d_ws;
        pool_all<<<W_T1 / 4, 256, 0, stream>>>(t1, t2, t3, t4, ws);
        combine<<<1568, 256, 0, stream>>>(ws, ff, out);
    } else {
        dim3 grid(7, 28, 8);
        fused_pool_relu<<<grid, 256, 0, stream>>>(t1, t2, t3, t4, ff, out);
    }
}